// Round 10
// baseline (273.471 us; speedup 1.0000x reference)
//
#include <hip/hip_runtime.h>

// Problem constants (from reference setup_inputs)
#define BATCH 4
#define CH    256
#define FH    200
#define FW    200
#define NROI  1024
#define PLANE (FH * FW)     // 40000
#define POOL  7
#define SAMP  8
#define NWAVE 16            // 1024 threads
#define LSTRIDE 204         // padded LDS row stride: 204 mod 32 = 12 -> 12*hi mod 32
                            // distinct for hi=0..7 (kills row-bank collisions);
                            // 204*200*4 = 163200 B <= 160 KiB, float4-aligned rows

// ---- workspace layout (int units unless noted) ----------------------------
// cnt[4] | idx[4][1024] | off[4][1024][64] | (float4, byte-offset) w4[4][1024][64]
#define WS_CNT 0
#define WS_IDX 4
#define WS_OFF (4 + BATCH * NROI)                       // 4100
#define WS_W4_BYTE ((size_t)(WS_OFF + BATCH * NROI * 64) * 4)  // 1064976, 16B-aligned
#define WS_NEEDED (WS_W4_BYTE + (size_t)BATCH * NROI * 64 * 16)

// ---------- pre-kernel: compact rois per image + per-lane gather records ----
// One wave per roi. Slot = deterministic rank among same-image rois (ballot
// scan, no atomics, no memset of poisoned ws). Record = LDS offset (stride
// 204) + bilinear weights with validity and the 0.25 pool factor folded in.
__global__ __launch_bounds__(64) void precompute_kernel(
    const float* __restrict__ rois, const float* __restrict__ scale_p,
    int* __restrict__ ws_i, float4* __restrict__ w4)
{
    const int n    = blockIdx.x;
    const int lane = threadIdx.x;
    const int ph   = lane >> 3;
    const int pw   = lane & 7;

    const int b_n = (int)rois[n * 5];

    // rank of n among rois of image b_n, + total count (uniform across lanes)
    int before = 0, total = 0;
    for (int k = 0; k < NROI / 64; ++k) {
        const int j  = (k << 6) + lane;
        const int bj = (int)rois[j * 5];
        const unsigned long long mask = __ballot(bj == b_n);
        total += __popcll(mask);
        const int lim = n - (k << 6);
        if (lim > 0) {
            const unsigned long long mm =
                (lim >= 64) ? mask : (mask & ((1ull << lim) - 1ull));
            before += __popcll(mm);
        }
    }
    const int slot = before;
    if (lane == 0) {
        ws_i[WS_IDX + (b_n << 10) + slot] = n;
        if (slot == 0) ws_i[WS_CNT + b_n] = total;   // first roi of image writes cnt
    }

    // geometry (identical math to the verified kernels)
    const float scale = scale_p[0];
    const float x1 = rois[n * 5 + 1] * scale;
    const float y1 = rois[n * 5 + 2] * scale;
    const float x2 = rois[n * 5 + 3] * scale;
    const float y2 = rois[n * 5 + 4] * scale;
    const float bin_h = fmaxf(y2 - y1 + 1.0f, 0.0f) * (1.0f / 7.0f);
    const float bin_w = fmaxf(x2 - x1 + 1.0f, 0.0f) * (1.0f / 7.0f);

    const float h    = y1 + (float)ph * bin_h;
    const float w    = x1 + (float)pw * bin_w;
    const float hs_f = fminf(floorf(h), (float)(FH - 2));
    const float ws_f = fminf(floorf(w), (float)(FW - 2));
    const float hr   = h - hs_f;
    const float wr   = w - ws_f;
    const int   hi   = (int)fmaxf(hs_f, 0.0f);   // [0,198]
    const int   wi   = (int)fmaxf(ws_f, 0.0f);   // [0,198]
    const bool  valid = (h >= 0.0f) && (h < (float)FH) &&
                        (w >= 0.0f) && (w < (float)FW);
    const float m = valid ? 0.25f : 0.0f;        // fold validity + pool scale

    float4 wv;
    wv.x = (1.0f - hr) * (1.0f - wr) * m;
    wv.y = (1.0f - hr) * wr * m;
    wv.z = hr * (1.0f - wr) * m;
    wv.w = hr * wr * m;

    const int rec = (((b_n << 10) + slot) << 6) + lane;
    ws_i[WS_OFF + rec] = hi * LSTRIDE + wi;
    w4[rec] = wv;
}

// ---------- main kernel: one wg per (channel, image) plane ------------------
// Phase 1: stage plane into LDS with padded stride 204 (coalesced float4 in,
//          conflict-spread rows). Phase 2: per roi-slot, load the precomputed
//          20B record (coalesced), 2x ds_read2_b32 for the 4 corners, 4 FMA,
//          two shfl_down for the 2x2 pool, masked nontemporal store.
//          Geometry math is NOT recomputed per channel (was ~3/4 of VALU work).
__global__ __launch_bounds__(1024, 1) void roialign_lds2_kernel(
    const float* __restrict__ feat,   // (B, C, H, W) f32
    const int*   __restrict__ ws_i,
    const float4* __restrict__ w4,
    float* __restrict__ out)          // (N, C, 7, 7) f32
{
    __shared__ float splane[LSTRIDE * FH];   // 163200 B

    const int c   = blockIdx.x;
    const int b   = blockIdx.y;
    const int tid = threadIdx.x;

    // ---- phase 1: stage full plane into LDS (padded stride) ----------------
    {
        const float4* __restrict__ src =
            (const float4*)(feat + ((size_t)b * CH + c) * PLANE);
        for (int j = tid; j < PLANE / 4; j += 1024) {   // 10000 float4s
            const int row = j / 50;                     // 50 float4 per row
            const int col = (j - row * 50) << 2;
            *(float4*)&splane[row * LSTRIDE + col] = src[j];
        }
    }
    __syncthreads();

    // ---- phase 2: roi slots of this image ----------------------------------
    const int wave = tid >> 6;
    const int lane = tid & 63;
    const int ph   = lane >> 3;
    const int pw   = lane & 7;
    const bool do_store = (ph < POOL) && (pw < POOL);

    int cntb = __builtin_amdgcn_readfirstlane(ws_i[WS_CNT + b]);
    cntb = (cntb > NROI) ? NROI : cntb;      // safety if image empty (poisoned)

#pragma unroll 2
    for (int i = wave; i < cntb; i += NWAVE) {
        const int n   = __builtin_amdgcn_readfirstlane(ws_i[WS_IDX + (b << 10) + i]);
        const int rec = (((b << 10) + i) << 6) + lane;

        const int    off = ws_i[WS_OFF + rec];   // hi*204 + wi
        const float4 wv  = w4[rec];

        // 4 corners: two ds_read2_b32 (off/off+1 and off+204/off+205)
        const float g00 = splane[off];
        const float g01 = splane[off + 1];
        const float g10 = splane[off + LSTRIDE];
        const float g11 = splane[off + LSTRIDE + 1];

        float v  = g00 * wv.x + g01 * wv.y + g10 * wv.z + g11 * wv.w;

        // 2x2 avg-pool across the 8x8 sample grid (0.25 already folded in)
        float s1 = v + __shfl_down(v, 1, 64);
        float s2 = s1 + __shfl_down(s1, 8, 64);

        if (do_store)
            __builtin_nontemporal_store(
                s2, out + ((size_t)n * CH + c) * (POOL * POOL) + ph * POOL + pw);
    }
}

// ---------- fallback (R4 global-gather, proven) if ws is too small ----------
#define CGROUPS 8
#define CH_PER_WAVE 8
__global__ __launch_bounds__(256) void roialign_gather_kernel(
    const float* __restrict__ feat, const float* __restrict__ rois,
    const float* __restrict__ scale_p, float* __restrict__ out)
{
    const int n = blockIdx.x, g = blockIdx.y, tid = threadIdx.x;
    const int wave = tid >> 6, lane = tid & 63;
    const int ph = lane >> 3, pw = lane & 7;
    const float scale = scale_p[0];
    const int   b  = (int)rois[n * 5 + 0];
    const float x1 = rois[n * 5 + 1] * scale, y1 = rois[n * 5 + 2] * scale;
    const float x2 = rois[n * 5 + 3] * scale, y2 = rois[n * 5 + 4] * scale;
    const float bin_h = fmaxf(y2 - y1 + 1.0f, 0.0f) / 7.0f;
    const float bin_w = fmaxf(x2 - x1 + 1.0f, 0.0f) / 7.0f;
    const float h = y1 + (float)ph * bin_h, w = x1 + (float)pw * bin_w;
    const float hs_f = fminf(floorf(h), (float)(FH - 2));
    const float ws_f = fminf(floorf(w), (float)(FW - 2));
    const float hr = h - hs_f, wr = w - ws_f;
    const int hi = (int)fmaxf(hs_f, 0.0f), wi = (int)fmaxf(ws_f, 0.0f);
    const bool valid = (h >= 0.0f) && (h < (float)FH) && (w >= 0.0f) && (w < (float)FW);
    const float m = valid ? 0.25f : 0.0f;
    const float w00 = (1.0f - hr) * (1.0f - wr) * m, w01 = (1.0f - hr) * wr * m;
    const float w10 = hr * (1.0f - wr) * m, w11 = hr * wr * m;
    const int c0 = g * (4 * CH_PER_WAVE) + wave * CH_PER_WAVE;
    const float* p = feat + ((size_t)(b * CH + c0)) * PLANE + (size_t)(hi * FW + wi);
    float* outp = out + ((size_t)n * CH + c0) * (POOL * POOL) + ph * POOL + pw;
    const bool do_store = (ph < POOL) && (pw < POOL);
#pragma unroll
    for (int dc = 0; dc < CH_PER_WAVE; ++dc) {
        float v = p[0] * w00 + p[1] * w01 + p[FW] * w10 + p[FW + 1] * w11;
        float s1 = v + __shfl_down(v, 1, 64);
        float s2 = s1 + __shfl_down(s1, 8, 64);
        if (do_store) __builtin_nontemporal_store(s2, outp);
        p += PLANE; outp += POOL * POOL;
    }
}

extern "C" void kernel_launch(void* const* d_in, const int* in_sizes, int n_in,
                              void* d_out, int out_size, void* d_ws, size_t ws_size,
                              hipStream_t stream) {
    const float* feat    = (const float*)d_in[0];  // (4,256,200,200) f32
    const float* rois    = (const float*)d_in[1];  // (1024,5) f32
    const float* scale_p = (const float*)d_in[2];  // scalar f32
    float*       out     = (float*)d_out;          // (1024,256,7,7) f32
    (void)in_sizes; (void)n_in; (void)out_size;

    if (ws_size >= WS_NEEDED) {
        int*    ws_i = (int*)d_ws;
        float4* w4   = (float4*)((char*)d_ws + WS_W4_BYTE);
        hipLaunchKernelGGL(precompute_kernel, dim3(NROI), dim3(64), 0, stream,
                           rois, scale_p, ws_i, w4);
        hipLaunchKernelGGL(roialign_lds2_kernel, dim3(CH, BATCH), dim3(1024), 0,
                           stream, feat, ws_i, w4, out);
    } else {
        hipLaunchKernelGGL(roialign_gather_kernel, dim3(NROI, CGROUPS), dim3(256),
                           0, stream, feat, rois, scale_p, out);
    }
}